// Round 2
// baseline (144.617 us; speedup 1.0000x reference)
//
#include <hip/hip_runtime.h>
#include <math.h>

#define UDIM 512
#define DIN  256
#define BATCH 128
#define EPSV 1e-3f

#define NCH  8     // column chunks per batch row
#define CHW  64    // columns per chunk
#define NSEG 32    // row segments per block
#define SEGH 16    // rows per segment (per-thread work)

// ---------------------------------------------------------------------------
// K1: pre = prev @ W_h + inputs @ C ; h = tanh(pre + bias)
// ---------------------------------------------------------------------------
__global__ __launch_bounds__(256) void k_pre(
    const float* __restrict__ inputs, const float* __restrict__ prev,
    const float* __restrict__ C, const float* __restrict__ Wh,
    const float* __restrict__ bias, float* __restrict__ pre, float* __restrict__ h)
{
    const int b = blockIdx.x >> 1;
    const int v = ((blockIdx.x & 1) << 8) + threadIdx.x;

    __shared__ float sprev[UDIM];
    __shared__ float sinp[DIN];
    for (int i = threadIdx.x; i < UDIM; i += 256) sprev[i] = prev[b * UDIM + i];
    sinp[threadIdx.x] = inputs[b * DIN + threadIdx.x];
    __syncthreads();

    float acc = 0.f;
#pragma unroll 8
    for (int u = 0; u < UDIM; ++u) acc = fmaf(sprev[u], Wh[u * UDIM + v], acc);
#pragma unroll 8
    for (int i = 0; i < DIN; ++i)  acc = fmaf(sinp[i], C[i * UDIM + v], acc);

    pre[b * UDIM + v] = acc;
    h[b * UDIM + v]   = tanhf(acc + bias[v]);
}

// ---------------------------------------------------------------------------
// K2 step 0: block (b, ch) streams A[b][:, ch*64..+63]:
//   A_new = 0.9*A + 0.5*h h^T (written), y = h @ A_new (accumulated)
//   hs = tanh(pre + y) -> hsout; per-chunk LN partial sums -> pstat
// grid = 128*8 = 1024 blocks x 512 threads
// ---------------------------------------------------------------------------
__global__ __launch_bounds__(512) void k_mv0(
    const float* __restrict__ A, const float* __restrict__ pre,
    const float* __restrict__ h, float* __restrict__ Anew,
    float* __restrict__ hsout, float* __restrict__ pstat)
{
    const int bc   = blockIdx.x;
    const int b    = bc >> 3;
    const int ch   = bc & 7;
    const int t    = threadIdx.x;
    const int vg   = t & 15;      // float4 group within chunk (16 x 4 = 64 cols)
    const int useg = t >> 4;      // 0..31 row segments

    __shared__ __align__(16) float sh[UDIM];
    __shared__ float spre[CHW];
    __shared__ __align__(16) float spart[NSEG][CHW];

    if (t < UDIM) sh[t] = h[(size_t)b * UDIM + t];
    if (t < CHW)  spre[t] = pre[(size_t)b * UDIM + ch * CHW + t];
    __syncthreads();

    const int gv0 = ch * CHW + vg * 4;
    const float4 hv4 = *(const float4*)(sh + gv0);
    const float* __restrict__ Ab  = A    + ((size_t)b * UDIM + useg * SEGH) * UDIM + gv0;
    float*       __restrict__ Anb = Anew + ((size_t)b * UDIM + useg * SEGH) * UDIM + gv0;

    float4 acc = make_float4(0.f, 0.f, 0.f, 0.f);
#pragma unroll 8
    for (int k = 0; k < SEGH; ++k) {
        const float4 a4 = *(const float4*)(Ab + (size_t)k * UDIM);
        const float hu = sh[useg * SEGH + k];
        const float s = 0.5f * hu;
        float4 an;
        an.x = fmaf(s, hv4.x, 0.9f * a4.x);
        an.y = fmaf(s, hv4.y, 0.9f * a4.y);
        an.z = fmaf(s, hv4.z, 0.9f * a4.z);
        an.w = fmaf(s, hv4.w, 0.9f * a4.w);
        *(float4*)(Anb + (size_t)k * UDIM) = an;
        acc.x = fmaf(hu, an.x, acc.x);
        acc.y = fmaf(hu, an.y, acc.y);
        acc.z = fmaf(hu, an.z, acc.z);
        acc.w = fmaf(hu, an.w, acc.w);
    }
    *(float4*)(&spart[useg][vg * 4]) = acc;
    __syncthreads();

    if (t < CHW) {
        float y = 0.f;
#pragma unroll
        for (int s = 0; s < NSEG; ++s) y += spart[s][t];
        const float hs = tanhf(spre[t] + y);
        hsout[(size_t)b * UDIM + ch * CHW + t] = hs;
        float s1 = hs, s2 = hs * hs;
#pragma unroll
        for (int off = 32; off; off >>= 1) {
            s1 += __shfl_xor(s1, off, 64);
            s2 += __shfl_xor(s2, off, 64);
        }
        if (t == 0) { pstat[bc * 2] = s1; pstat[bc * 2 + 1] = s2; }
    }
}

// ---------------------------------------------------------------------------
// K3 steps 1,2: x = LN(hs_prev) built from hs+partial stats; stream A_new
// (L3-hot): y = x @ A_new; hs = tanh(pre+y) -> hsout, partials -> pstout
// ---------------------------------------------------------------------------
__global__ __launch_bounds__(512) void k_mv(
    const float* __restrict__ An, const float* __restrict__ pre,
    const float* __restrict__ hsin, const float* __restrict__ pstin,
    const float* __restrict__ gamma, const float* __restrict__ beta,
    float* __restrict__ hsout, float* __restrict__ pstout)
{
    const int bc   = blockIdx.x;
    const int b    = bc >> 3;
    const int ch   = bc & 7;
    const int t    = threadIdx.x;
    const int vg   = t & 15;
    const int useg = t >> 4;

    __shared__ __align__(16) float sx[UDIM];
    __shared__ float spre[CHW];
    __shared__ __align__(16) float spart[NSEG][CHW];
    __shared__ float sbc[2];

    if (t == 0) {
        float m = 0.f, q = 0.f;
#pragma unroll
        for (int i = 0; i < NCH; ++i) {
            m += pstin[(b * NCH + i) * 2];
            q += pstin[(b * NCH + i) * 2 + 1];
        }
        m *= (1.f / UDIM);
        q = q * (1.f / UDIM) - m * m;
        sbc[0] = m;
        sbc[1] = rsqrtf(q + EPSV);
    }
    if (t < CHW) spre[t] = pre[(size_t)b * UDIM + ch * CHW + t];
    __syncthreads();
    if (t < UDIM) {
        const float hv = hsin[(size_t)b * UDIM + t];
        sx[t] = (hv - sbc[0]) * sbc[1] * gamma[t] + beta[t];
    }
    __syncthreads();

    const int gv0 = ch * CHW + vg * 4;
    const float* __restrict__ Ab = An + ((size_t)b * UDIM + useg * SEGH) * UDIM + gv0;

    float4 acc = make_float4(0.f, 0.f, 0.f, 0.f);
#pragma unroll 8
    for (int k = 0; k < SEGH; ++k) {
        const float4 a4 = *(const float4*)(Ab + (size_t)k * UDIM);
        const float xu = sx[useg * SEGH + k];
        acc.x = fmaf(xu, a4.x, acc.x);
        acc.y = fmaf(xu, a4.y, acc.y);
        acc.z = fmaf(xu, a4.z, acc.z);
        acc.w = fmaf(xu, a4.w, acc.w);
    }
    *(float4*)(&spart[useg][vg * 4]) = acc;
    __syncthreads();

    if (t < CHW) {
        float y = 0.f;
#pragma unroll
        for (int s = 0; s < NSEG; ++s) y += spart[s][t];
        const float hs = tanhf(spre[t] + y);
        hsout[(size_t)b * UDIM + ch * CHW + t] = hs;
        float s1 = hs, s2 = hs * hs;
#pragma unroll
        for (int off = 32; off; off >>= 1) {
            s1 += __shfl_xor(s1, off, 64);
            s2 += __shfl_xor(s2, off, 64);
        }
        if (t == 0) { pstout[bc * 2] = s1; pstout[bc * 2 + 1] = s2; }
    }
}

// ---------------------------------------------------------------------------
// K4: out = LN(hs2)
// ---------------------------------------------------------------------------
__global__ __launch_bounds__(512) void k_fin(
    const float* __restrict__ hsin, const float* __restrict__ pstin,
    const float* __restrict__ gamma, const float* __restrict__ beta,
    float* __restrict__ out)
{
    const int b = blockIdx.x;
    const int t = threadIdx.x;
    __shared__ float sbc[2];
    if (t == 0) {
        float m = 0.f, q = 0.f;
#pragma unroll
        for (int i = 0; i < NCH; ++i) {
            m += pstin[(b * NCH + i) * 2];
            q += pstin[(b * NCH + i) * 2 + 1];
        }
        m *= (1.f / UDIM);
        q = q * (1.f / UDIM) - m * m;
        sbc[0] = m;
        sbc[1] = rsqrtf(q + EPSV);
    }
    __syncthreads();
    if (t < UDIM) {
        const float hv = hsin[(size_t)b * UDIM + t];
        out[(size_t)b * UDIM + t] = (hv - sbc[0]) * sbc[1] * gamma[t] + beta[t];
    }
}

// ---------------------------------------------------------------------------
extern "C" void kernel_launch(void* const* d_in, const int* in_sizes, int n_in,
                              void* d_out, int out_size, void* d_ws, size_t ws_size,
                              hipStream_t stream) {
    const float* inputs = (const float*)d_in[0];
    const float* prev   = (const float*)d_in[1];
    const float* A      = (const float*)d_in[2];
    const float* C      = (const float*)d_in[3];
    const float* Wh     = (const float*)d_in[4];
    const float* bias   = (const float*)d_in[5];
    const float* gamma  = (const float*)d_in[6];
    const float* beta   = (const float*)d_in[7];

    float* out  = (float*)d_out;                  // (128,512)
    float* Anew = out + (size_t)BATCH * UDIM;     // (128,512,512)

    float* pre  = (float*)d_ws;                       // 128*512
    float* h    = pre  + (size_t)BATCH * UDIM;        // 128*512
    float* hsA  = h    + (size_t)BATCH * UDIM;        // 128*512
    float* hsB  = hsA  + (size_t)BATCH * UDIM;        // 128*512
    float* pstA = hsB  + (size_t)BATCH * UDIM;        // 128*8*2
    float* pstB = pstA + (size_t)BATCH * NCH * 2;     // 128*8*2

    k_pre<<<BATCH * 2, 256, 0, stream>>>(inputs, prev, C, Wh, bias, pre, h);
    k_mv0<<<BATCH * NCH, 512, 0, stream>>>(A, pre, h, Anew, hsA, pstA);
    k_mv <<<BATCH * NCH, 512, 0, stream>>>(Anew, pre, hsA, pstA, gamma, beta, hsB, pstB);
    k_mv <<<BATCH * NCH, 512, 0, stream>>>(Anew, pre, hsB, pstB, gamma, beta, hsA, pstA);
    k_fin<<<BATCH, 512, 0, stream>>>(hsA, pstA, gamma, beta, out);
}

// Round 4
// 132.729 us; speedup vs baseline: 1.0896x; 1.0896x over previous
//
#include <hip/hip_runtime.h>
#include <math.h>

#define UDIM 512
#define DIN  256
#define BATCH 128
#define EPSV 1e-3f

#define NRSEG 8      // row segments per batch (blocks per batch)
#define RPB   64     // rows per block
#define HALFR 32     // rows per thread-half

typedef float f4 __attribute__((ext_vector_type(4)));

// ---------------------------------------------------------------------------
// K1: pre = prev @ W_h + inputs @ C ; h = tanh(pre + bias)
// ---------------------------------------------------------------------------
__global__ __launch_bounds__(256) void k_pre(
    const float* __restrict__ inputs, const float* __restrict__ prev,
    const float* __restrict__ C, const float* __restrict__ Wh,
    const float* __restrict__ bias, float* __restrict__ pre, float* __restrict__ h)
{
    const int b = blockIdx.x >> 1;
    const int v = ((blockIdx.x & 1) << 8) + threadIdx.x;

    __shared__ float sprev[UDIM];
    __shared__ float sinp[DIN];
    for (int i = threadIdx.x; i < UDIM; i += 256) sprev[i] = prev[b * UDIM + i];
    sinp[threadIdx.x] = inputs[b * DIN + threadIdx.x];
    __syncthreads();

    float acc = 0.f;
#pragma unroll 8
    for (int u = 0; u < UDIM; ++u) acc = fmaf(sprev[u], Wh[u * UDIM + v], acc);
#pragma unroll 8
    for (int i = 0; i < DIN; ++i)  acc = fmaf(sinp[i], C[i * UDIM + v], acc);

    pre[b * UDIM + v] = acc;
    h[b * UDIM + v]   = tanhf(acc + bias[v]);
}

// ---------------------------------------------------------------------------
// K2 step 0: block (b, rseg) streams 64 FULL rows of A[b] (contiguous 128KB):
//   A_new = 0.9*A + 0.5*h h^T (written, cached), A read NON-TEMPORAL.
//   partial y0[v] = sum_{u in slab} h_u * A_new[u][v]  -> ypart
// grid = 128*8 = 1024 blocks x 256 threads
// ---------------------------------------------------------------------------
__global__ __launch_bounds__(256) void k_mv0(
    const float* __restrict__ A, const float* __restrict__ h,
    float* __restrict__ Anew, float* __restrict__ ypart)
{
    const int bc   = blockIdx.x;
    const int b    = bc >> 3;
    const int rs   = bc & 7;
    const int t    = threadIdx.x;
    const int vg   = t & 127;      // float4 col group (128 x 4 = 512 cols)
    const int col  = vg << 2;
    const int half = t >> 7;       // 0/1 -> rows half*32..+31

    __shared__ __align__(16) float sh[UDIM];
    __shared__ __align__(16) float spart[2][UDIM];

    sh[t]       = h[(size_t)b * UDIM + t];
    sh[t + 256] = h[(size_t)b * UDIM + t + 256];
    __syncthreads();

    const f4 hv4 = *(const f4*)(sh + col);
    const int row0 = rs * RPB + half * HALFR;
    const float* __restrict__ Ab  = A    + ((size_t)b * UDIM + row0) * UDIM + col;
    float*       __restrict__ Anb = Anew + ((size_t)b * UDIM + row0) * UDIM + col;

    f4 acc = {0.f, 0.f, 0.f, 0.f};
#pragma unroll 8
    for (int k = 0; k < HALFR; ++k) {
        const f4 a4 = __builtin_nontemporal_load((const f4*)(Ab + (size_t)k * UDIM));
        const float hu = sh[row0 + k];
        const float s = 0.5f * hu;
        f4 an;
        an.x = fmaf(s, hv4.x, 0.9f * a4.x);
        an.y = fmaf(s, hv4.y, 0.9f * a4.y);
        an.z = fmaf(s, hv4.z, 0.9f * a4.z);
        an.w = fmaf(s, hv4.w, 0.9f * a4.w);
        *(f4*)(Anb + (size_t)k * UDIM) = an;
        acc.x = fmaf(hu, an.x, acc.x);
        acc.y = fmaf(hu, an.y, acc.y);
        acc.z = fmaf(hu, an.z, acc.z);
        acc.w = fmaf(hu, an.w, acc.w);
    }
    *(f4*)(&spart[half][col]) = acc;
    __syncthreads();

    {
        const float y0 = spart[0][t]       + spart[1][t];
        const float y1 = spart[0][t + 256] + spart[1][t + 256];
        ypart[(size_t)bc * UDIM + t]       = y0;
        ypart[(size_t)bc * UDIM + t + 256] = y1;
    }
}

// ---------------------------------------------------------------------------
// K3 steps 1,2: block (b, rseg):
//   y = sum_s ypin[b][s][:]; hs = tanh(pre+y); LN -> x (redundant per rseg)
//   partial y'[v] = sum_{u in slab} x_u * Anew[u][v] -> ypout  (Anew L3-hot)
// ---------------------------------------------------------------------------
__global__ __launch_bounds__(256) void k_mv(
    const float* __restrict__ An, const float* __restrict__ pre,
    const float* __restrict__ ypin, const float* __restrict__ gamma,
    const float* __restrict__ beta, float* __restrict__ ypout)
{
    const int bc   = blockIdx.x;
    const int b    = bc >> 3;
    const int rs   = bc & 7;
    const int t    = threadIdx.x;
    const int lane = t & 63;
    const int wave = t >> 6;       // 0..3
    const int vg   = t & 127;
    const int col  = vg << 2;
    const int half = t >> 7;

    __shared__ __align__(16) float sx[UDIM];
    __shared__ float shs[UDIM];
    __shared__ __align__(16) float spart[2][UDIM];
    __shared__ float sred[8];
    __shared__ float sbc[2];

    // combine partials -> hs (each thread handles cols t and t+256)
    {
        float y0 = 0.f, y1 = 0.f;
#pragma unroll
        for (int s = 0; s < NRSEG; ++s) {
            y0 += ypin[((size_t)b * NRSEG + s) * UDIM + t];
            y1 += ypin[((size_t)b * NRSEG + s) * UDIM + t + 256];
        }
        const float hs0 = tanhf(pre[(size_t)b * UDIM + t] + y0);
        const float hs1 = tanhf(pre[(size_t)b * UDIM + t + 256] + y1);
        shs[t] = hs0; shs[t + 256] = hs1;
        float s1 = hs0 + hs1, s2 = hs0 * hs0 + hs1 * hs1;
#pragma unroll
        for (int off = 32; off; off >>= 1) {
            s1 += __shfl_xor(s1, off, 64);
            s2 += __shfl_xor(s2, off, 64);
        }
        if (lane == 0) { sred[wave] = s1; sred[4 + wave] = s2; }
    }
    __syncthreads();
    if (t == 0) {
        float m = sred[0] + sred[1] + sred[2] + sred[3];
        float q = sred[4] + sred[5] + sred[6] + sred[7];
        m *= (1.f / UDIM);
        q = q * (1.f / UDIM) - m * m;
        sbc[0] = m;
        sbc[1] = rsqrtf(q + EPSV);
    }
    __syncthreads();
    {
        const float m = sbc[0], r = sbc[1];
        sx[t]       = (shs[t]       - m) * r * gamma[t]       + beta[t];
        sx[t + 256] = (shs[t + 256] - m) * r * gamma[t + 256] + beta[t + 256];
    }
    __syncthreads();

    const int row0 = rs * RPB + half * HALFR;
    const float* __restrict__ Ab = An + ((size_t)b * UDIM + row0) * UDIM + col;

    f4 acc = {0.f, 0.f, 0.f, 0.f};
#pragma unroll 8
    for (int k = 0; k < HALFR; ++k) {
        const f4 a4 = *(const f4*)(Ab + (size_t)k * UDIM);
        const float xu = sx[row0 + k];
        acc.x = fmaf(xu, a4.x, acc.x);
        acc.y = fmaf(xu, a4.y, acc.y);
        acc.z = fmaf(xu, a4.z, acc.z);
        acc.w = fmaf(xu, a4.w, acc.w);
    }
    *(f4*)(&spart[half][col]) = acc;
    __syncthreads();

    {
        const float y0 = spart[0][t]       + spart[1][t];
        const float y1 = spart[0][t + 256] + spart[1][t + 256];
        ypout[(size_t)bc * UDIM + t]       = y0;
        ypout[(size_t)bc * UDIM + t + 256] = y1;
    }
}

// ---------------------------------------------------------------------------
// K4: out = LN(tanh(pre + sum ypart))
// ---------------------------------------------------------------------------
__global__ __launch_bounds__(512) void k_fin(
    const float* __restrict__ pre, const float* __restrict__ ypin,
    const float* __restrict__ gamma, const float* __restrict__ beta,
    float* __restrict__ out)
{
    const int b    = blockIdx.x;
    const int t    = threadIdx.x;
    const int lane = t & 63;
    const int wave = t >> 6;   // 0..7

    __shared__ float sred[16];
    __shared__ float sbc[2];

    float y = 0.f;
#pragma unroll
    for (int s = 0; s < NRSEG; ++s) y += ypin[((size_t)b * NRSEG + s) * UDIM + t];
    const float hs = tanhf(pre[(size_t)b * UDIM + t] + y);

    float s1 = hs, s2 = hs * hs;
#pragma unroll
    for (int off = 32; off; off >>= 1) {
        s1 += __shfl_xor(s1, off, 64);
        s2 += __shfl_xor(s2, off, 64);
    }
    if (lane == 0) { sred[wave] = s1; sred[8 + wave] = s2; }
    __syncthreads();
    if (t == 0) {
        float m = 0.f, q = 0.f;
#pragma unroll
        for (int i = 0; i < 8; ++i) { m += sred[i]; q += sred[8 + i]; }
        m *= (1.f / UDIM);
        q = q * (1.f / UDIM) - m * m;
        sbc[0] = m;
        sbc[1] = rsqrtf(q + EPSV);
    }
    __syncthreads();
    out[(size_t)b * UDIM + t] = (hs - sbc[0]) * sbc[1] * gamma[t] + beta[t];
}

// ---------------------------------------------------------------------------
extern "C" void kernel_launch(void* const* d_in, const int* in_sizes, int n_in,
                              void* d_out, int out_size, void* d_ws, size_t ws_size,
                              hipStream_t stream) {
    const float* inputs = (const float*)d_in[0];
    const float* prev   = (const float*)d_in[1];
    const float* A      = (const float*)d_in[2];
    const float* C      = (const float*)d_in[3];
    const float* Wh     = (const float*)d_in[4];
    const float* bias   = (const float*)d_in[5];
    const float* gamma  = (const float*)d_in[6];
    const float* beta   = (const float*)d_in[7];

    float* out  = (float*)d_out;                  // (128,512)
    float* Anew = out + (size_t)BATCH * UDIM;     // (128,512,512)

    float* pre  = (float*)d_ws;                         // 128*512
    float* h    = pre  + (size_t)BATCH * UDIM;          // 128*512
    float* ypA  = h    + (size_t)BATCH * UDIM;          // 128*8*512
    float* ypB  = ypA  + (size_t)BATCH * NRSEG * UDIM;  // 128*8*512

    k_pre<<<BATCH * 2, 256, 0, stream>>>(inputs, prev, C, Wh, bias, pre, h);
    k_mv0<<<BATCH * NRSEG, 256, 0, stream>>>(A, h, Anew, ypA);
    k_mv <<<BATCH * NRSEG, 256, 0, stream>>>(Anew, pre, ypA, gamma, beta, ypB);
    k_mv <<<BATCH * NRSEG, 256, 0, stream>>>(Anew, pre, ypB, gamma, beta, ypA);
    k_fin<<<BATCH, 512, 0, stream>>>(pre, ypA, gamma, beta, out);
}

// Round 5
// 131.095 us; speedup vs baseline: 1.1031x; 1.0125x over previous
//
#include <hip/hip_runtime.h>
#include <math.h>

#define UDIM 512
#define DIN  256
#define BATCH 128
#define EPSV 1e-3f

#define NRSEG 8      // row segments per batch (blocks per batch)
#define RPB   64     // rows per block
#define HALFR 32     // rows per thread-half

typedef float f4 __attribute__((ext_vector_type(4)));

// ---------------------------------------------------------------------------
// K1: pre = prev @ W_h + inputs @ C ; h = tanh(pre + bias)
// ---------------------------------------------------------------------------
__global__ __launch_bounds__(256) void k_pre(
    const float* __restrict__ inputs, const float* __restrict__ prev,
    const float* __restrict__ C, const float* __restrict__ Wh,
    const float* __restrict__ bias, float* __restrict__ pre, float* __restrict__ h)
{
    const int b = blockIdx.x >> 1;
    const int v = ((blockIdx.x & 1) << 8) + threadIdx.x;

    __shared__ float sprev[UDIM];
    __shared__ float sinp[DIN];
    for (int i = threadIdx.x; i < UDIM; i += 256) sprev[i] = prev[b * UDIM + i];
    sinp[threadIdx.x] = inputs[b * DIN + threadIdx.x];
    __syncthreads();

    float acc = 0.f;
#pragma unroll 8
    for (int u = 0; u < UDIM; ++u) acc = fmaf(sprev[u], Wh[u * UDIM + v], acc);
#pragma unroll 8
    for (int i = 0; i < DIN; ++i)  acc = fmaf(sinp[i], C[i * UDIM + v], acc);

    pre[b * UDIM + v] = acc;
    h[b * UDIM + v]   = tanhf(acc + bias[v]);
}

// ---------------------------------------------------------------------------
// K2 (read-only): block (b, rs) streams 64 rows of A[b] (regular loads ->
// populate L3; A is re-read by the two k_mv steps).
//   partial[v] = sum_{u in slab} h_u * A[u][v] -> ypart (RAW, no 0.9/0.5)
//   rs==0 also writes dot_hh[b] = h.h
// ---------------------------------------------------------------------------
__global__ __launch_bounds__(256) void k_mv0ro(
    const float* __restrict__ A, const float* __restrict__ h,
    float* __restrict__ ypart, float* __restrict__ dotout)
{
    const int bc   = blockIdx.x;
    const int b    = bc >> 3;
    const int rs   = bc & 7;
    const int t    = threadIdx.x;
    const int lane = t & 63;
    const int wave = t >> 6;
    const int vg   = t & 127;
    const int col  = vg << 2;
    const int half = t >> 7;

    __shared__ __align__(16) float sh[UDIM];
    __shared__ __align__(16) float spart[2][UDIM];
    __shared__ float sred[4];

    sh[t]       = h[(size_t)b * UDIM + t];
    sh[t + 256] = h[(size_t)b * UDIM + t + 256];
    __syncthreads();

    // h.h partial (combined after main loop)
    float dp = sh[t] * sh[t] + sh[t + 256] * sh[t + 256];
#pragma unroll
    for (int off = 32; off; off >>= 1) dp += __shfl_xor(dp, off, 64);
    if (lane == 0) sred[wave] = dp;

    const int row0 = rs * RPB + half * HALFR;
    const float* __restrict__ Ab = A + ((size_t)b * UDIM + row0) * UDIM + col;

    f4 acc = {0.f, 0.f, 0.f, 0.f};
#pragma unroll 8
    for (int k = 0; k < HALFR; ++k) {
        const f4 a4 = *(const f4*)(Ab + (size_t)k * UDIM);
        const float hu = sh[row0 + k];
        acc.x = fmaf(hu, a4.x, acc.x);
        acc.y = fmaf(hu, a4.y, acc.y);
        acc.z = fmaf(hu, a4.z, acc.z);
        acc.w = fmaf(hu, a4.w, acc.w);
    }
    *(f4*)(&spart[half][col]) = acc;
    __syncthreads();

    {
        const float y0 = spart[0][t]       + spart[1][t];
        const float y1 = spart[0][t + 256] + spart[1][t + 256];
        ypart[(size_t)bc * UDIM + t]       = y0;
        ypart[(size_t)bc * UDIM + t + 256] = y1;
    }
    if (rs == 0 && t == 0)
        dotout[b] = sred[0] + sred[1] + sred[2] + sred[3];
}

// ---------------------------------------------------------------------------
// K3 (steps 1,2): block (b, rs):
//   y = 0.9*sum_s ypin + 0.5*dotin[b]*h ; hs = tanh(pre+y); x = LN(hs)
//   partial[v] = sum_{u in slab} x_u * A[u][v] -> ypout (RAW)
//   dotout[b] = x.h (rs==0)
//   threads with half==wh also write A_new = 0.9A + 0.5 h h^T for their
//   32 rows, NON-TEMPORAL (A_new is never read again).
// ---------------------------------------------------------------------------
__global__ __launch_bounds__(256) void k_mv(
    const float* __restrict__ A, float* __restrict__ Anew,
    const float* __restrict__ pre, const float* __restrict__ h,
    const float* __restrict__ ypin, const float* __restrict__ dotin,
    const float* __restrict__ gamma, const float* __restrict__ beta,
    float* __restrict__ ypout, float* __restrict__ dotout, const int wh)
{
    const int bc   = blockIdx.x;
    const int b    = bc >> 3;
    const int rs   = bc & 7;
    const int t    = threadIdx.x;
    const int lane = t & 63;
    const int wave = t >> 6;       // 0..3
    const int vg   = t & 127;
    const int col  = vg << 2;
    const int half = t >> 7;

    __shared__ __align__(16) float sh[UDIM];
    __shared__ __align__(16) float sx[UDIM];
    __shared__ float shs[UDIM];
    __shared__ __align__(16) float spart[2][UDIM];
    __shared__ float sred[8];
    __shared__ float sred2[4];
    __shared__ float sbc[2];

    sh[t]       = h[(size_t)b * UDIM + t];
    sh[t + 256] = h[(size_t)b * UDIM + t + 256];

    // combine partials -> hs
    {
        float y0 = 0.f, y1 = 0.f;
#pragma unroll
        for (int s = 0; s < NRSEG; ++s) {
            y0 += ypin[((size_t)b * NRSEG + s) * UDIM + t];
            y1 += ypin[((size_t)b * NRSEG + s) * UDIM + t + 256];
        }
        const float d = 0.5f * dotin[b];
        y0 = fmaf(0.9f, y0, d * sh[t]);
        y1 = fmaf(0.9f, y1, d * sh[t + 256]);
        const float hs0 = tanhf(pre[(size_t)b * UDIM + t] + y0);
        const float hs1 = tanhf(pre[(size_t)b * UDIM + t + 256] + y1);
        shs[t] = hs0; shs[t + 256] = hs1;
        float s1 = hs0 + hs1, s2 = hs0 * hs0 + hs1 * hs1;
#pragma unroll
        for (int off = 32; off; off >>= 1) {
            s1 += __shfl_xor(s1, off, 64);
            s2 += __shfl_xor(s2, off, 64);
        }
        if (lane == 0) { sred[wave] = s1; sred[4 + wave] = s2; }
    }
    __syncthreads();
    if (t == 0) {
        float m = sred[0] + sred[1] + sred[2] + sred[3];
        float q = sred[4] + sred[5] + sred[6] + sred[7];
        m *= (1.f / UDIM);
        q = q * (1.f / UDIM) - m * m;
        sbc[0] = m;
        sbc[1] = rsqrtf(q + EPSV);
    }
    __syncthreads();
    {
        const float m = sbc[0], r = sbc[1];
        sx[t]       = (shs[t]       - m) * r * gamma[t]       + beta[t];
        sx[t + 256] = (shs[t + 256] - m) * r * gamma[t + 256] + beta[t + 256];
    }
    __syncthreads();

    // x.h partial (combined after main loop)
    {
        float dp = sx[t] * sh[t] + sx[t + 256] * sh[t + 256];
#pragma unroll
        for (int off = 32; off; off >>= 1) dp += __shfl_xor(dp, off, 64);
        if (lane == 0) sred2[wave] = dp;
    }

    const int row0 = rs * RPB + half * HALFR;
    const float* __restrict__ Ab  = A    + ((size_t)b * UDIM + row0) * UDIM + col;
    float*       __restrict__ Anb = Anew + ((size_t)b * UDIM + row0) * UDIM + col;
    const f4 hv4 = *(const f4*)(sh + col);

    f4 acc = {0.f, 0.f, 0.f, 0.f};
    if (half == wh) {
#pragma unroll 8
        for (int k = 0; k < HALFR; ++k) {
            const f4 a4 = *(const f4*)(Ab + (size_t)k * UDIM);
            const float xu = sx[row0 + k];
            const float s  = 0.5f * sh[row0 + k];
            f4 an;
            an.x = fmaf(s, hv4.x, 0.9f * a4.x);
            an.y = fmaf(s, hv4.y, 0.9f * a4.y);
            an.z = fmaf(s, hv4.z, 0.9f * a4.z);
            an.w = fmaf(s, hv4.w, 0.9f * a4.w);
            __builtin_nontemporal_store(an, (f4*)(Anb + (size_t)k * UDIM));
            acc.x = fmaf(xu, a4.x, acc.x);
            acc.y = fmaf(xu, a4.y, acc.y);
            acc.z = fmaf(xu, a4.z, acc.z);
            acc.w = fmaf(xu, a4.w, acc.w);
        }
    } else {
#pragma unroll 8
        for (int k = 0; k < HALFR; ++k) {
            const f4 a4 = *(const f4*)(Ab + (size_t)k * UDIM);
            const float xu = sx[row0 + k];
            acc.x = fmaf(xu, a4.x, acc.x);
            acc.y = fmaf(xu, a4.y, acc.y);
            acc.z = fmaf(xu, a4.z, acc.z);
            acc.w = fmaf(xu, a4.w, acc.w);
        }
    }
    *(f4*)(&spart[half][col]) = acc;
    __syncthreads();

    {
        const float y0 = spart[0][t]       + spart[1][t];
        const float y1 = spart[0][t + 256] + spart[1][t + 256];
        ypout[(size_t)bc * UDIM + t]       = y0;
        ypout[(size_t)bc * UDIM + t + 256] = y1;
    }
    if (rs == 0 && t == 0)
        dotout[b] = sred2[0] + sred2[1] + sred2[2] + sred2[3];
}

// ---------------------------------------------------------------------------
// K4: out = LN(tanh(pre + 0.9*sum ypart + 0.5*dot*h))
// ---------------------------------------------------------------------------
__global__ __launch_bounds__(512) void k_fin(
    const float* __restrict__ pre, const float* __restrict__ h,
    const float* __restrict__ ypin, const float* __restrict__ dotin,
    const float* __restrict__ gamma, const float* __restrict__ beta,
    float* __restrict__ out)
{
    const int b    = blockIdx.x;
    const int t    = threadIdx.x;
    const int lane = t & 63;
    const int wave = t >> 6;   // 0..7

    __shared__ float sred[16];
    __shared__ float sbc[2];

    float y = 0.f;
#pragma unroll
    for (int s = 0; s < NRSEG; ++s) y += ypin[((size_t)b * NRSEG + s) * UDIM + t];
    y = fmaf(0.9f, y, 0.5f * dotin[b] * h[(size_t)b * UDIM + t]);
    const float hs = tanhf(pre[(size_t)b * UDIM + t] + y);

    float s1 = hs, s2 = hs * hs;
#pragma unroll
    for (int off = 32; off; off >>= 1) {
        s1 += __shfl_xor(s1, off, 64);
        s2 += __shfl_xor(s2, off, 64);
    }
    if (lane == 0) { sred[wave] = s1; sred[8 + wave] = s2; }
    __syncthreads();
    if (t == 0) {
        float m = 0.f, q = 0.f;
#pragma unroll
        for (int i = 0; i < 8; ++i) { m += sred[i]; q += sred[8 + i]; }
        m *= (1.f / UDIM);
        q = q * (1.f / UDIM) - m * m;
        sbc[0] = m;
        sbc[1] = rsqrtf(q + EPSV);
    }
    __syncthreads();
    out[(size_t)b * UDIM + t] = (hs - sbc[0]) * sbc[1] * gamma[t] + beta[t];
}

// ---------------------------------------------------------------------------
extern "C" void kernel_launch(void* const* d_in, const int* in_sizes, int n_in,
                              void* d_out, int out_size, void* d_ws, size_t ws_size,
                              hipStream_t stream) {
    const float* inputs = (const float*)d_in[0];
    const float* prev   = (const float*)d_in[1];
    const float* A      = (const float*)d_in[2];
    const float* C      = (const float*)d_in[3];
    const float* Wh     = (const float*)d_in[4];
    const float* bias   = (const float*)d_in[5];
    const float* gamma  = (const float*)d_in[6];
    const float* beta   = (const float*)d_in[7];

    float* out  = (float*)d_out;                  // (128,512)
    float* Anew = out + (size_t)BATCH * UDIM;     // (128,512,512)

    float* pre  = (float*)d_ws;                         // 128*512
    float* h    = pre  + (size_t)BATCH * UDIM;          // 128*512
    float* ypA  = h    + (size_t)BATCH * UDIM;          // 128*8*512
    float* ypB  = ypA  + (size_t)BATCH * NRSEG * UDIM;  // 128*8*512
    float* dotH = ypB  + (size_t)BATCH * NRSEG * UDIM;  // 128
    float* dot1 = dotH + BATCH;                         // 128
    float* dot2 = dot1 + BATCH;                         // 128

    k_pre  <<<BATCH * 2, 256, 0, stream>>>(inputs, prev, C, Wh, bias, pre, h);
    k_mv0ro<<<BATCH * NRSEG, 256, 0, stream>>>(A, h, ypA, dotH);
    k_mv   <<<BATCH * NRSEG, 256, 0, stream>>>(A, Anew, pre, h, ypA, dotH,
                                               gamma, beta, ypB, dot1, 0);
    k_mv   <<<BATCH * NRSEG, 256, 0, stream>>>(A, Anew, pre, h, ypB, dot1,
                                               gamma, beta, ypA, dot2, 1);
    k_fin  <<<BATCH, 512, 0, stream>>>(pre, h, ypA, dot2, gamma, beta, out);
}